// Round 1
// baseline (1371.789 us; speedup 1.0000x reference)
//
#include <hip/hip_runtime.h>

// DeltanetHead: T=4096, B=8, C=1024, F=128
// R4: barrier-drain fix. __syncthreads() emits s_waitcnt vmcnt(0) before
// s_barrier, flushing the prefetch ring every 8-step batch (512 flushes x
// ~full memory latency). Replace with lgkmcnt(0)-only + raw s_barrier so
// the P-stream prefetches stay in flight across batches (T4: counted vmcnt,
// never drain). Ring deepened 4 -> 8 slots; prefetch clamp dropped (reads
// overrun <=196KB into the adjacent allocated ob region, never consumed).

#define T_DIM 4096
#define B_DIM 8
#define C_DIM 1024
#define F_DIM 128

typedef __attribute__((ext_vector_type(8))) short bf16x8;
typedef __attribute__((ext_vector_type(4))) float f32x4;

__device__ __forceinline__ unsigned short f2bf(float f) {
  unsigned u = __float_as_uint(f);
  u += 0x7fffu + ((u >> 16) & 1u);   // round-to-nearest-even
  return (unsigned short)(u >> 16);
}
__device__ __forceinline__ float bfu2f(unsigned u) { return __uint_as_float(u << 16); }

// ---------------- elementwise fp32 -> bf16 convert (vectorized x4) ----------------
__global__ void cvt_kernel(const float* __restrict__ in, unsigned short* __restrict__ out, int n4) {
  int i = blockIdx.x * blockDim.x + threadIdx.x;
  int stride = gridDim.x * blockDim.x;
  for (; i < n4; i += stride) {
    float4 v = ((const float4*)in)[i];
    ushort4 r;
    r.x = f2bf(v.x); r.y = f2bf(v.y); r.z = f2bf(v.z); r.w = f2bf(v.w);
    ((ushort4*)out)[i] = r;
  }
}

// ---------------- pack 6 [F][C] weights -> Wall[768][1024] bf16 + bias[768] ----------------
__global__ void pack_w_kernel(const float* __restrict__ Aw, const float* __restrict__ Ab,
                              const float* __restrict__ Bw, const float* __restrict__ Bb,
                              const float* __restrict__ Cw, const float* __restrict__ Cb,
                              const float* __restrict__ Dw, const float* __restrict__ Db,
                              const float* __restrict__ Iw, const float* __restrict__ Ib,
                              const float* __restrict__ Sw, const float* __restrict__ Sb,
                              unsigned short* __restrict__ Wall, float* __restrict__ biasAll) {
  const float scaleB = 0.08838834764831845f;  // 1/sqrt(128), folded into b-projection
  int idx = blockIdx.x * 256 + threadIdx.x;
  if (idx < 768 * 1024) {
    int row = idx >> 10, c = idx & 1023;
    int slot = row >> 7, rr = row & 127;
    const float* W = slot == 0 ? Aw : slot == 1 ? Bw : slot == 2 ? Cw
                   : slot == 3 ? Dw : slot == 4 ? Iw : Sw;
    float v = W[rr * 1024 + c];
    if (slot == 1) v *= scaleB;
    Wall[idx] = f2bf(v);
  }
  if (idx < 768) {
    int slot = idx >> 7, rr = idx & 127;
    const float* Bv = slot == 0 ? Ab : slot == 1 ? Bb : slot == 2 ? Cb
                    : slot == 3 ? Db : slot == 4 ? Ib : Sb;
    float v = Bv[rr];
    if (slot == 1) v *= scaleB;
    biasAll[idx] = v;
  }
}

// ---------------- bf16 MFMA GEMM: C[M][N] = A[M][K] * B[N][K]^T (+bias, +sigmoid range) ----------------
__global__ __launch_bounds__(256) void gemm_bt(
    const unsigned short* __restrict__ A,
    const unsigned short* __restrict__ Bm,
    float* __restrict__ Cm,
    const float* __restrict__ bias,
    int M, int N, int K, int sig_lo, int sig_hi) {
  __shared__ unsigned short As[128 * 32];
  __shared__ unsigned short Bs[128 * 32];
  const int tid = threadIdx.x;
  const int m0 = blockIdx.x * 128;
  const int n0 = blockIdx.y * 128;
  const int wv = tid >> 6, ln = tid & 63;
  const int mo = (wv & 1) * 64, no = (wv >> 1) * 64;
  const int lrow = ln & 15, lq = ln >> 4;
  f32x4 acc[4][4] = {};

  for (int kt = 0; kt < K; kt += 32) {
#pragma unroll
    for (int it = 0; it < 2; ++it) {
      int idx = it * 256 + tid;
      int row = idx >> 2, kc = idx & 3;
      *(int4*)&As[row * 32 + kc * 8] = *(const int4*)&A[(size_t)(m0 + row) * K + kt + kc * 8];
      *(int4*)&Bs[row * 32 + kc * 8] = *(const int4*)&Bm[(size_t)(n0 + row) * K + kt + kc * 8];
    }
    __syncthreads();
    bf16x8 af[4], bf[4];
#pragma unroll
    for (int i = 0; i < 4; ++i) {
      af[i] = *(const bf16x8*)&As[(mo + i * 16 + lrow) * 32 + lq * 8];
      bf[i] = *(const bf16x8*)&Bs[(no + i * 16 + lrow) * 32 + lq * 8];
    }
#pragma unroll
    for (int i = 0; i < 4; ++i)
#pragma unroll
      for (int j = 0; j < 4; ++j)
        acc[i][j] = __builtin_amdgcn_mfma_f32_16x16x32_bf16(af[i], bf[j], acc[i][j], 0, 0, 0);
    __syncthreads();
  }

#pragma unroll
  for (int i = 0; i < 4; ++i) {
#pragma unroll
    for (int j = 0; j < 4; ++j) {
      int col = n0 + no + j * 16 + lrow;
      float bv = bias ? bias[col] : 0.0f;
      bool sig = (col >= sig_lo) && (col < sig_hi);
#pragma unroll
      for (int r = 0; r < 4; ++r) {
        int row = m0 + mo + i * 16 + lq * 4 + r;
        float v = acc[i][j][r] + bv;
        if (sig) v = 1.0f / (1.0f + __expf(-v));
        Cm[(size_t)row * N + col] = v;
      }
    }
  }
}

// ---------------- wave-wide sum via DPP ----------------
__device__ __forceinline__ float wave_sum64(float x) {
  x += __int_as_float(__builtin_amdgcn_update_dpp(0, __float_as_int(x), 0x111, 0xf, 0xf, false)); // row_shr:1
  x += __int_as_float(__builtin_amdgcn_update_dpp(0, __float_as_int(x), 0x112, 0xf, 0xf, false)); // row_shr:2
  x += __int_as_float(__builtin_amdgcn_update_dpp(0, __float_as_int(x), 0x114, 0xf, 0xf, false)); // row_shr:4
  x += __int_as_float(__builtin_amdgcn_update_dpp(0, __float_as_int(x), 0x118, 0xf, 0xf, false)); // row_shr:8
  x += __int_as_float(__builtin_amdgcn_update_dpp(0, __float_as_int(x), 0x142, 0xf, 0xf, false)); // row_bcast:15
  x += __int_as_float(__builtin_amdgcn_update_dpp(0, __float_as_int(x), 0x143, 0xf, 0xf, false)); // row_bcast:31
  return __int_as_float(__builtin_amdgcn_readlane(__float_as_int(x), 63));
}

// ---------------- sequential scan ----------------
// grid (B, G), 256 thr (4 waves). Wave owns ROWS rows, lane owns 2 cols.
// 8-slot register ring prefetches P 8 steps ahead; LDS cross-wave reduce
// once per 8 steps behind a lgkmcnt-only barrier (parity double-buffered)
// so the vmem prefetch ring is NEVER drained inside the loop.
template <int ROWS>
__global__ __launch_bounds__(256) void scan_kernel(
    const float* __restrict__ P,          // [T][B][6][128] fp32
    const float* __restrict__ state_in,   // [B][128][128]
    unsigned short* __restrict__ o_part,  // [G][T][B][128] bf16
    float* __restrict__ state_out) {      // [B][128][128]
  const int b = blockIdx.x;
  const int gq = blockIdx.y;
  const int wave = threadIdx.x >> 6;
  const int lane = threadIdx.x & 63;
  const int r0 = gq * (4 * ROWS) + wave * ROWS;
  const int j0 = lane * 2;
  __shared__ float buf[2][4][8][128];   // [parity][wave][step-in-batch][col] = 32 KB

  float2 st[ROWS];
#pragma unroll
  for (int r = 0; r < ROWS; ++r)
    st[r] = *(const float2*)&state_in[((size_t)b * F_DIM + r0 + r) * F_DIM + j0];

  // 8-slot prefetch ring (distance-8; tail prefetches overrun past P's end
  // into the adjacent allocated ob region and are never consumed)
  float2 Pa[8], Pb[8], Pd[8], Pg[8];
  float Pc[8][ROWS], Ps[8][ROWS];
  const size_t PSTEP = (size_t)B_DIM * 768;
  const float* P0 = P + (size_t)b * 768;

#define RING_LOAD(sl, Pt)                                                   \
  do {                                                                      \
    Pa[sl] = *(const float2*)((Pt) + 0 + j0);                               \
    Pb[sl] = *(const float2*)((Pt) + 128 + j0);                             \
    Pd[sl] = *(const float2*)((Pt) + 384 + j0);                             \
    Pg[sl] = *(const float2*)((Pt) + 512 + j0);                             \
    if constexpr (ROWS == 2) {                                              \
      float2 v_ = *(const float2*)((Pt) + 256 + r0);                        \
      Pc[sl][0] = v_.x; Pc[sl][1] = v_.y;                                   \
      float2 w_ = *(const float2*)((Pt) + 640 + r0);                        \
      Ps[sl][0] = w_.x; Ps[sl][1] = w_.y;                                   \
    } else {                                                                \
      float4 v_ = *(const float4*)((Pt) + 256 + r0);                        \
      Pc[sl][0] = v_.x; Pc[sl][1] = v_.y; Pc[sl][2] = v_.z; Pc[sl][3] = v_.w; \
      float4 w_ = *(const float4*)((Pt) + 640 + r0);                        \
      Ps[sl][0] = w_.x; Ps[sl][1] = w_.y; Ps[sl][2] = w_.z; Ps[sl][3] = w_.w; \
    }                                                                       \
  } while (0)

#pragma unroll
  for (int k = 0; k < 8; ++k) RING_LOAD(k, P0 + (size_t)k * PSTEP);

  for (int t8 = 0; t8 < T_DIM; t8 += 8) {
    const int pb = (t8 >> 3) & 1;
#pragma unroll
    for (int k = 0; k < 8; ++k) {
      // grab current step's values (SSA copies; regalloc coalesces)
      float2 a2 = Pa[k], b2 = Pb[k], d2 = Pd[k], g2 = Pg[k];
      float cc[ROWS], ss[ROWS];
#pragma unroll
      for (int r = 0; r < ROWS; ++r) { cc[r] = Pc[k][r]; ss[r] = Ps[k][r]; }

      // issue prefetch for step t+8 into this slot (off the dependency chain)
      const float* Pn = P0 + (size_t)(t8 + k + 8) * PSTEP;
      RING_LOAD(k, Pn);

      // v[r] = st[r,:] . a  (old state, wave-wide reduce over 128 cols)
      float vr[ROWS];
#pragma unroll
      for (int r = 0; r < ROWS; ++r)
        vr[r] = wave_sum64(st[r].x * a2.x + st[r].y * a2.y);

      // st update + partial out over this wave's rows
      float ox = 0.0f, oy = 0.0f;
#pragma unroll
      for (int r = 0; r < ROWS; ++r) {
        st[r].x = st[r].x * g2.x + vr[r] * b2.x + cc[r] * d2.x;
        st[r].y = st[r].y * g2.y + vr[r] * b2.y + cc[r] * d2.y;
        ox += ss[r] * st[r].x;
        oy += ss[r] * st[r].y;
      }
      *(float2*)&buf[pb][wave][k][j0] = make_float2(ox, oy);
    }
    // LDS-only barrier: orders the buf writes without draining the vmem
    // prefetch ring (__syncthreads would emit s_waitcnt vmcnt(0)).
    asm volatile("s_waitcnt lgkmcnt(0)" ::: "memory");
    __builtin_amdgcn_s_barrier();
    asm volatile("" ::: "memory");

    // cross-wave reduce of the 8-step batch: 512 items = 8 steps x 64 col-pairs
#pragma unroll
    for (int h = 0; h < 2; ++h) {
      int it = threadIdx.x + h * 256;
      int k = it >> 6, c2 = (it & 63) * 2;
      float2 s0 = *(const float2*)&buf[pb][0][k][c2];
      float2 s1 = *(const float2*)&buf[pb][1][k][c2];
      float2 s2 = *(const float2*)&buf[pb][2][k][c2];
      float2 s3 = *(const float2*)&buf[pb][3][k][c2];
      float sx = s0.x + s1.x + s2.x + s3.x;
      float sy = s0.y + s1.y + s2.y + s3.y;
      unsigned pk = (unsigned)f2bf(sx) | ((unsigned)f2bf(sy) << 16);
      *(unsigned*)&o_part[(((size_t)gq * T_DIM + t8 + k) * B_DIM + b) * F_DIM + c2] = pk;
    }
    // no second barrier: parity double-buffer + the next batch's barrier orders reuse
  }
#undef RING_LOAD

#pragma unroll
  for (int r = 0; r < ROWS; ++r)
    *(float2*)&state_out[((size_t)b * F_DIM + r0 + r) * F_DIM + j0] = st[r];
}

// ---------------- sum G bf16 partials -> ob bf16 (memory-bound) ----------------
__global__ void reduce_kernel(const unsigned short* __restrict__ o_part,
                              unsigned short* __restrict__ ob, int G) {
  const size_t NEL = (size_t)T_DIM * B_DIM * F_DIM;  // 4,194,304
  size_t i = ((size_t)blockIdx.x * 256 + threadIdx.x) * 8;
  if (i >= NEL) return;
  float acc[8] = {0, 0, 0, 0, 0, 0, 0, 0};
  for (int g = 0; g < G; ++g) {
    int4 v = *(const int4*)(o_part + (size_t)g * NEL + i);
    unsigned w0 = (unsigned)v.x, w1 = (unsigned)v.y, w2 = (unsigned)v.z, w3 = (unsigned)v.w;
    acc[0] += bfu2f(w0 & 0xffffu); acc[1] += bfu2f(w0 >> 16);
    acc[2] += bfu2f(w1 & 0xffffu); acc[3] += bfu2f(w1 >> 16);
    acc[4] += bfu2f(w2 & 0xffffu); acc[5] += bfu2f(w2 >> 16);
    acc[6] += bfu2f(w3 & 0xffffu); acc[7] += bfu2f(w3 >> 16);
  }
  int4 o;
  o.x = (int)((unsigned)f2bf(acc[0]) | ((unsigned)f2bf(acc[1]) << 16));
  o.y = (int)((unsigned)f2bf(acc[2]) | ((unsigned)f2bf(acc[3]) << 16));
  o.z = (int)((unsigned)f2bf(acc[4]) | ((unsigned)f2bf(acc[5]) << 16));
  o.w = (int)((unsigned)f2bf(acc[6]) | ((unsigned)f2bf(acc[7]) << 16));
  *(int4*)(ob + i) = o;
}

extern "C" void kernel_launch(void* const* d_in, const int* in_sizes, int n_in,
                              void* d_out, int out_size, void* d_ws, size_t ws_size,
                              hipStream_t stream) {
  const float* x  = (const float*)d_in[0];
  const float* st = (const float*)d_in[1];
  const float* Aw = (const float*)d_in[2];
  const float* Ab = (const float*)d_in[3];
  const float* Bw = (const float*)d_in[4];
  const float* Bb = (const float*)d_in[5];
  const float* Cw = (const float*)d_in[6];
  const float* Cb = (const float*)d_in[7];
  const float* Dw = (const float*)d_in[8];
  const float* Db = (const float*)d_in[9];
  const float* Iw = (const float*)d_in[10];
  const float* Ib = (const float*)d_in[11];
  const float* Sw = (const float*)d_in[12];
  const float* Sb = (const float*)d_in[13];
  const float* Ow = (const float*)d_in[14];

  float* y = (float*)d_out;                               // [T][B][C]
  float* state_out = y + (size_t)T_DIM * B_DIM * C_DIM;   // [B][F][F]

  // workspace carve:
  //   Wall      @ 0           (1,572,864)
  //   biasAll   @ 1,572,864   (3,072, padded)
  //   Owb       @ 1,576,960   (262,144)
  //   P         @ 1,839,104   (100,663,296)
  //   ob        @ 102,502,400 (8,388,608)
  //   xb        @ 110,891,008 (67,108,864)  -- dead after proj GEMM
  //   o_part    @ 110,891,008 (G * 8,388,608) reuses xb region; G=16 extends past it
  char* ws = (char*)d_ws;
  unsigned short* Wall = (unsigned short*)(ws);
  float* biasAll       = (float*)(ws + 1572864);
  unsigned short* Owb  = (unsigned short*)(ws + 1576960);
  float* P             = (float*)(ws + 1839104);
  unsigned short* ob   = (unsigned short*)(ws + 102502400);
  unsigned short* xb   = (unsigned short*)(ws + 110891008);
  unsigned short* o_part = xb;

  // G=16 wants 110,891,008 + 16*8,388,608 = 245,108,736 bytes of ws
  const int G = (ws_size >= 245108736u) ? 16 : 8;

  cvt_kernel<<<4096, 256, 0, stream>>>(x, xb, 33554432 / 4);
  pack_w_kernel<<<3072, 256, 0, stream>>>(Aw, Ab, Bw, Bb, Cw, Cb, Dw, Db, Iw, Ib, Sw, Sb,
                                          Wall, biasAll);
  cvt_kernel<<<128, 256, 0, stream>>>(Ow, Owb, 131072 / 4);
  // projections: P = x @ Wall^T + bias, sigmoid on I-slot cols [512,640)
  gemm_bt<<<dim3(256, 6), 256, 0, stream>>>(xb, Wall, P, biasAll, 32768, 768, 1024, 512, 640);
  if (G == 16)
    scan_kernel<2><<<dim3(8, 16), 256, 0, stream>>>(P, st, o_part, state_out);
  else
    scan_kernel<4><<<dim3(8, 8), 256, 0, stream>>>(P, st, o_part, state_out);
  reduce_kernel<<<2048, 256, 0, stream>>>(o_part, ob, G);
  // y = o @ O_w^T
  gemm_bt<<<dim3(256, 8), 256, 0, stream>>>(ob, Owb, y, nullptr, 32768, 1024, 128, 0, 0);
}

// Round 2
// 1271.657 us; speedup vs baseline: 1.0787x; 1.0787x over previous
//
#include <hip/hip_runtime.h>

// DeltanetHead: T=4096, B=8, C=1024, F=128
// R5: make the prefetch ring REAL. R3/R4 evidence: VGPR_Count (56/76) is
// smaller than the ring's register footprint (48/96) => the compiler's
// occupancy-driven pressure heuristics were sinking/spilling the ring, so
// every step paid an exposed L2/L3 load latency (~400 cyc) on the serial
// chain (526 cyc/step measured). Fix: __launch_bounds__(256, 1) lifts the
// VGPR budget to 512 (1 wave/EU is all we can use anyway -- wall time of
// the scan is per-block serial time, occupancy does not matter), and a
// sched_barrier(0) at each step end pins the slot-(t+8) load issue inside
// its step. Batch barrier stays lgkmcnt-only so the ring survives batches.

#define T_DIM 4096
#define B_DIM 8
#define C_DIM 1024
#define F_DIM 128

typedef __attribute__((ext_vector_type(8))) short bf16x8;
typedef __attribute__((ext_vector_type(4))) float f32x4;

__device__ __forceinline__ unsigned short f2bf(float f) {
  unsigned u = __float_as_uint(f);
  u += 0x7fffu + ((u >> 16) & 1u);   // round-to-nearest-even
  return (unsigned short)(u >> 16);
}
__device__ __forceinline__ float bfu2f(unsigned u) { return __uint_as_float(u << 16); }

// ---------------- elementwise fp32 -> bf16 convert (vectorized x4) ----------------
__global__ void cvt_kernel(const float* __restrict__ in, unsigned short* __restrict__ out, int n4) {
  int i = blockIdx.x * blockDim.x + threadIdx.x;
  int stride = gridDim.x * blockDim.x;
  for (; i < n4; i += stride) {
    float4 v = ((const float4*)in)[i];
    ushort4 r;
    r.x = f2bf(v.x); r.y = f2bf(v.y); r.z = f2bf(v.z); r.w = f2bf(v.w);
    ((ushort4*)out)[i] = r;
  }
}

// ---------------- pack 6 [F][C] weights -> Wall[768][1024] bf16 + bias[768] ----------------
__global__ void pack_w_kernel(const float* __restrict__ Aw, const float* __restrict__ Ab,
                              const float* __restrict__ Bw, const float* __restrict__ Bb,
                              const float* __restrict__ Cw, const float* __restrict__ Cb,
                              const float* __restrict__ Dw, const float* __restrict__ Db,
                              const float* __restrict__ Iw, const float* __restrict__ Ib,
                              const float* __restrict__ Sw, const float* __restrict__ Sb,
                              unsigned short* __restrict__ Wall, float* __restrict__ biasAll) {
  const float scaleB = 0.08838834764831845f;  // 1/sqrt(128), folded into b-projection
  int idx = blockIdx.x * 256 + threadIdx.x;
  if (idx < 768 * 1024) {
    int row = idx >> 10, c = idx & 1023;
    int slot = row >> 7, rr = row & 127;
    const float* W = slot == 0 ? Aw : slot == 1 ? Bw : slot == 2 ? Cw
                   : slot == 3 ? Dw : slot == 4 ? Iw : Sw;
    float v = W[rr * 1024 + c];
    if (slot == 1) v *= scaleB;
    Wall[idx] = f2bf(v);
  }
  if (idx < 768) {
    int slot = idx >> 7, rr = idx & 127;
    const float* Bv = slot == 0 ? Ab : slot == 1 ? Bb : slot == 2 ? Cb
                    : slot == 3 ? Db : slot == 4 ? Ib : Sb;
    float v = Bv[rr];
    if (slot == 1) v *= scaleB;
    biasAll[idx] = v;
  }
}

// ---------------- bf16 MFMA GEMM: C[M][N] = A[M][K] * B[N][K]^T (+bias, +sigmoid range) ----------------
__global__ __launch_bounds__(256) void gemm_bt(
    const unsigned short* __restrict__ A,
    const unsigned short* __restrict__ Bm,
    float* __restrict__ Cm,
    const float* __restrict__ bias,
    int M, int N, int K, int sig_lo, int sig_hi) {
  __shared__ unsigned short As[128 * 32];
  __shared__ unsigned short Bs[128 * 32];
  const int tid = threadIdx.x;
  const int m0 = blockIdx.x * 128;
  const int n0 = blockIdx.y * 128;
  const int wv = tid >> 6, ln = tid & 63;
  const int mo = (wv & 1) * 64, no = (wv >> 1) * 64;
  const int lrow = ln & 15, lq = ln >> 4;
  f32x4 acc[4][4] = {};

  for (int kt = 0; kt < K; kt += 32) {
#pragma unroll
    for (int it = 0; it < 2; ++it) {
      int idx = it * 256 + tid;
      int row = idx >> 2, kc = idx & 3;
      *(int4*)&As[row * 32 + kc * 8] = *(const int4*)&A[(size_t)(m0 + row) * K + kt + kc * 8];
      *(int4*)&Bs[row * 32 + kc * 8] = *(const int4*)&Bm[(size_t)(n0 + row) * K + kt + kc * 8];
    }
    __syncthreads();
    bf16x8 af[4], bf[4];
#pragma unroll
    for (int i = 0; i < 4; ++i) {
      af[i] = *(const bf16x8*)&As[(mo + i * 16 + lrow) * 32 + lq * 8];
      bf[i] = *(const bf16x8*)&Bs[(no + i * 16 + lrow) * 32 + lq * 8];
    }
#pragma unroll
    for (int i = 0; i < 4; ++i)
#pragma unroll
      for (int j = 0; j < 4; ++j)
        acc[i][j] = __builtin_amdgcn_mfma_f32_16x16x32_bf16(af[i], bf[j], acc[i][j], 0, 0, 0);
    __syncthreads();
  }

#pragma unroll
  for (int i = 0; i < 4; ++i) {
#pragma unroll
    for (int j = 0; j < 4; ++j) {
      int col = n0 + no + j * 16 + lrow;
      float bv = bias ? bias[col] : 0.0f;
      bool sig = (col >= sig_lo) && (col < sig_hi);
#pragma unroll
      for (int r = 0; r < 4; ++r) {
        int row = m0 + mo + i * 16 + lq * 4 + r;
        float v = acc[i][j][r] + bv;
        if (sig) v = 1.0f / (1.0f + __expf(-v));
        Cm[(size_t)row * N + col] = v;
      }
    }
  }
}

// ---------------- wave-wide sum via DPP ----------------
__device__ __forceinline__ float wave_sum64(float x) {
  x += __int_as_float(__builtin_amdgcn_update_dpp(0, __float_as_int(x), 0x111, 0xf, 0xf, false)); // row_shr:1
  x += __int_as_float(__builtin_amdgcn_update_dpp(0, __float_as_int(x), 0x112, 0xf, 0xf, false)); // row_shr:2
  x += __int_as_float(__builtin_amdgcn_update_dpp(0, __float_as_int(x), 0x114, 0xf, 0xf, false)); // row_shr:4
  x += __int_as_float(__builtin_amdgcn_update_dpp(0, __float_as_int(x), 0x118, 0xf, 0xf, false)); // row_shr:8
  x += __int_as_float(__builtin_amdgcn_update_dpp(0, __float_as_int(x), 0x142, 0xf, 0xf, false)); // row_bcast:15
  x += __int_as_float(__builtin_amdgcn_update_dpp(0, __float_as_int(x), 0x143, 0xf, 0xf, false)); // row_bcast:31
  return __int_as_float(__builtin_amdgcn_readlane(__float_as_int(x), 63));
}

// ---------------- sequential scan ----------------
// grid (B, G), 256 thr (4 waves). Wave owns ROWS rows, lane owns 2 cols.
// 8-slot register ring prefetches P 8 steps ahead. __launch_bounds__(256,1)
// gives the RA a 512-VGPR budget so the ring (96 VGPR) stays RESIDENT;
// sched_barrier(0) per step pins the load issue inside its step. LDS
// cross-wave reduce once per 8 steps behind a lgkmcnt-only barrier
// (parity double-buffered) so the vmem ring is never drained in-loop.
template <int ROWS>
__global__ __launch_bounds__(256, 1) void scan_kernel(
    const float* __restrict__ P,          // [T][B][6][128] fp32
    const float* __restrict__ state_in,   // [B][128][128]
    unsigned short* __restrict__ o_part,  // [G][T][B][128] bf16
    float* __restrict__ state_out) {      // [B][128][128]
  const int b = blockIdx.x;
  const int gq = blockIdx.y;
  const int wave = threadIdx.x >> 6;
  const int lane = threadIdx.x & 63;
  const int r0 = gq * (4 * ROWS) + wave * ROWS;
  const int j0 = lane * 2;
  __shared__ float buf[2][4][8][128];   // [parity][wave][step-in-batch][col] = 32 KB

  float2 st[ROWS];
#pragma unroll
  for (int r = 0; r < ROWS; ++r)
    st[r] = *(const float2*)&state_in[((size_t)b * F_DIM + r0 + r) * F_DIM + j0];

  // 8-slot prefetch ring (distance-8; tail prefetches overrun past P's end
  // into the adjacent allocated ob region and are never consumed)
  float2 Pa[8], Pb[8], Pd[8], Pg[8];
  float Pc[8][ROWS], Ps[8][ROWS];
  const size_t PSTEP = (size_t)B_DIM * 768;
  const float* P0 = P + (size_t)b * 768;

#define RING_LOAD(sl, Pt)                                                   \
  do {                                                                      \
    Pa[sl] = *(const float2*)((Pt) + 0 + j0);                               \
    Pb[sl] = *(const float2*)((Pt) + 128 + j0);                             \
    Pd[sl] = *(const float2*)((Pt) + 384 + j0);                             \
    Pg[sl] = *(const float2*)((Pt) + 512 + j0);                             \
    if constexpr (ROWS == 2) {                                              \
      float2 v_ = *(const float2*)((Pt) + 256 + r0);                        \
      Pc[sl][0] = v_.x; Pc[sl][1] = v_.y;                                   \
      float2 w_ = *(const float2*)((Pt) + 640 + r0);                        \
      Ps[sl][0] = w_.x; Ps[sl][1] = w_.y;                                   \
    } else {                                                                \
      float4 v_ = *(const float4*)((Pt) + 256 + r0);                        \
      Pc[sl][0] = v_.x; Pc[sl][1] = v_.y; Pc[sl][2] = v_.z; Pc[sl][3] = v_.w; \
      float4 w_ = *(const float4*)((Pt) + 640 + r0);                        \
      Ps[sl][0] = w_.x; Ps[sl][1] = w_.y; Ps[sl][2] = w_.z; Ps[sl][3] = w_.w; \
    }                                                                       \
  } while (0)

#pragma unroll
  for (int k = 0; k < 8; ++k) RING_LOAD(k, P0 + (size_t)k * PSTEP);

  for (int t8 = 0; t8 < T_DIM; t8 += 8) {
    const int pb = (t8 >> 3) & 1;
#pragma unroll
    for (int k = 0; k < 8; ++k) {
      // grab current step's values (SSA copies; regalloc coalesces)
      float2 a2 = Pa[k], b2 = Pb[k], d2 = Pd[k], g2 = Pg[k];
      float cc[ROWS], ss[ROWS];
#pragma unroll
      for (int r = 0; r < ROWS; ++r) { cc[r] = Pc[k][r]; ss[r] = Ps[k][r]; }

      // issue prefetch for step t+8 into this slot (off the dependency chain)
      const float* Pn = P0 + (size_t)(t8 + k + 8) * PSTEP;
      RING_LOAD(k, Pn);

      // v[r] = st[r,:] . a  (old state, wave-wide reduce over 128 cols)
      float vr[ROWS];
#pragma unroll
      for (int r = 0; r < ROWS; ++r)
        vr[r] = wave_sum64(st[r].x * a2.x + st[r].y * a2.y);

      // st update + partial out over this wave's rows
      float ox = 0.0f, oy = 0.0f;
#pragma unroll
      for (int r = 0; r < ROWS; ++r) {
        st[r].x = st[r].x * g2.x + vr[r] * b2.x + cc[r] * d2.x;
        st[r].y = st[r].y * g2.y + vr[r] * b2.y + cc[r] * d2.y;
        ox += ss[r] * st[r].x;
        oy += ss[r] * st[r].y;
      }
      *(float2*)&buf[pb][wave][k][j0] = make_float2(ox, oy);
      // pin this step's region: the slot-(t+8) loads above may not sink
      // into later steps; later compute may not hoist above.
      __builtin_amdgcn_sched_barrier(0);
    }
    // LDS-only barrier: orders the buf writes without draining the vmem
    // prefetch ring (__syncthreads would emit s_waitcnt vmcnt(0)).
    asm volatile("s_waitcnt lgkmcnt(0)" ::: "memory");
    __builtin_amdgcn_s_barrier();
    asm volatile("" ::: "memory");

    // cross-wave reduce of the 8-step batch: 512 items = 8 steps x 64 col-pairs
#pragma unroll
    for (int h = 0; h < 2; ++h) {
      int it = threadIdx.x + h * 256;
      int k = it >> 6, c2 = (it & 63) * 2;
      float2 s0 = *(const float2*)&buf[pb][0][k][c2];
      float2 s1 = *(const float2*)&buf[pb][1][k][c2];
      float2 s2 = *(const float2*)&buf[pb][2][k][c2];
      float2 s3 = *(const float2*)&buf[pb][3][k][c2];
      float sx = s0.x + s1.x + s2.x + s3.x;
      float sy = s0.y + s1.y + s2.y + s3.y;
      unsigned pk = (unsigned)f2bf(sx) | ((unsigned)f2bf(sy) << 16);
      *(unsigned*)&o_part[(((size_t)gq * T_DIM + t8 + k) * B_DIM + b) * F_DIM + c2] = pk;
    }
    // no second barrier: parity double-buffer + the next batch's barrier orders reuse
  }
#undef RING_LOAD

#pragma unroll
  for (int r = 0; r < ROWS; ++r)
    *(float2*)&state_out[((size_t)b * F_DIM + r0 + r) * F_DIM + j0] = st[r];
}

// ---------------- sum G bf16 partials -> ob bf16 (memory-bound) ----------------
__global__ void reduce_kernel(const unsigned short* __restrict__ o_part,
                              unsigned short* __restrict__ ob, int G) {
  const size_t NEL = (size_t)T_DIM * B_DIM * F_DIM;  // 4,194,304
  size_t i = ((size_t)blockIdx.x * 256 + threadIdx.x) * 8;
  if (i >= NEL) return;
  float acc[8] = {0, 0, 0, 0, 0, 0, 0, 0};
  for (int g = 0; g < G; ++g) {
    int4 v = *(const int4*)(o_part + (size_t)g * NEL + i);
    unsigned w0 = (unsigned)v.x, w1 = (unsigned)v.y, w2 = (unsigned)v.z, w3 = (unsigned)v.w;
    acc[0] += bfu2f(w0 & 0xffffu); acc[1] += bfu2f(w0 >> 16);
    acc[2] += bfu2f(w1 & 0xffffu); acc[3] += bfu2f(w1 >> 16);
    acc[4] += bfu2f(w2 & 0xffffu); acc[5] += bfu2f(w2 >> 16);
    acc[6] += bfu2f(w3 & 0xffffu); acc[7] += bfu2f(w3 >> 16);
  }
  int4 o;
  o.x = (int)((unsigned)f2bf(acc[0]) | ((unsigned)f2bf(acc[1]) << 16));
  o.y = (int)((unsigned)f2bf(acc[2]) | ((unsigned)f2bf(acc[3]) << 16));
  o.z = (int)((unsigned)f2bf(acc[4]) | ((unsigned)f2bf(acc[5]) << 16));
  o.w = (int)((unsigned)f2bf(acc[6]) | ((unsigned)f2bf(acc[7]) << 16));
  *(int4*)(ob + i) = o;
}

extern "C" void kernel_launch(void* const* d_in, const int* in_sizes, int n_in,
                              void* d_out, int out_size, void* d_ws, size_t ws_size,
                              hipStream_t stream) {
  const float* x  = (const float*)d_in[0];
  const float* st = (const float*)d_in[1];
  const float* Aw = (const float*)d_in[2];
  const float* Ab = (const float*)d_in[3];
  const float* Bw = (const float*)d_in[4];
  const float* Bb = (const float*)d_in[5];
  const float* Cw = (const float*)d_in[6];
  const float* Cb = (const float*)d_in[7];
  const float* Dw = (const float*)d_in[8];
  const float* Db = (const float*)d_in[9];
  const float* Iw = (const float*)d_in[10];
  const float* Ib = (const float*)d_in[11];
  const float* Sw = (const float*)d_in[12];
  const float* Sb = (const float*)d_in[13];
  const float* Ow = (const float*)d_in[14];

  float* y = (float*)d_out;                               // [T][B][C]
  float* state_out = y + (size_t)T_DIM * B_DIM * C_DIM;   // [B][F][F]

  // workspace carve:
  //   Wall      @ 0           (1,572,864)
  //   biasAll   @ 1,572,864   (3,072, padded)
  //   Owb       @ 1,576,960   (262,144)
  //   P         @ 1,839,104   (100,663,296)
  //   ob        @ 102,502,400 (8,388,608)
  //   xb        @ 110,891,008 (67,108,864)  -- dead after proj GEMM
  //   o_part    @ 110,891,008 (G * 8,388,608) reuses xb region; G=16 extends past it
  char* ws = (char*)d_ws;
  unsigned short* Wall = (unsigned short*)(ws);
  float* biasAll       = (float*)(ws + 1572864);
  unsigned short* Owb  = (unsigned short*)(ws + 1576960);
  float* P             = (float*)(ws + 1839104);
  unsigned short* ob   = (unsigned short*)(ws + 102502400);
  unsigned short* xb   = (unsigned short*)(ws + 110891008);
  unsigned short* o_part = xb;

  // G=16 wants 110,891,008 + 16*8,388,608 = 245,108,736 bytes of ws
  const int G = (ws_size >= 245108736u) ? 16 : 8;

  cvt_kernel<<<4096, 256, 0, stream>>>(x, xb, 33554432 / 4);
  pack_w_kernel<<<3072, 256, 0, stream>>>(Aw, Ab, Bw, Bb, Cw, Cb, Dw, Db, Iw, Ib, Sw, Sb,
                                          Wall, biasAll);
  cvt_kernel<<<128, 256, 0, stream>>>(Ow, Owb, 131072 / 4);
  // projections: P = x @ Wall^T + bias, sigmoid on I-slot cols [512,640)
  gemm_bt<<<dim3(256, 6), 256, 0, stream>>>(xb, Wall, P, biasAll, 32768, 768, 1024, 512, 640);
  if (G == 16)
    scan_kernel<2><<<dim3(8, 16), 256, 0, stream>>>(P, st, o_part, state_out);
  else
    scan_kernel<4><<<dim3(8, 8), 256, 0, stream>>>(P, st, o_part, state_out);
  reduce_kernel<<<2048, 256, 0, stream>>>(o_part, ob, G);
  // y = o @ O_w^T
  gemm_bt<<<dim3(256, 8), 256, 0, stream>>>(ob, Owb, y, nullptr, 32768, 1024, 128, 0, 0);
}